// Round 3
// baseline (1611.263 us; speedup 1.0000x reference)
//
#include <hip/hip_runtime.h>
#include <stdint.h>

// Fused transformer block on MI355X (gfx950), *fp16* MFMA pipeline
// (fp16 = same MFMA rate as bf16, 8x smaller rounding error; all magnitudes
//  in this network fit fp16 range).
// Adaptive workspace plan:
//  Tier A (ws >= 386 MB): full-batch GEMMs
//  Tier B (otherwise, needs 62.9 MB): per-batch pipeline with buffer aliasing
// FC epilogue (bias+relu+residual) writes fp32 into d_out, LayerNorm in-place.
// GEMM: m97 structure (128x128 tile, BK=32, 4 waves, global_load_lds width 16).

#define DEVI __device__ __forceinline__

typedef uint16_t u16;
typedef _Float16 f16x8 __attribute__((ext_vector_type(8)));
typedef float f32x4 __attribute__((ext_vector_type(4)));

DEVI u16 f2h(float f) {  // fp32 -> fp16 bits (RNE via v_cvt_f16_f32)
  union { _Float16 h; u16 u; } v;
  v.h = (_Float16)f;
  return v.u;
}

DEVI void gload_lds16(const void* g, void* lds) {
  __builtin_amdgcn_global_load_lds(
      (const __attribute__((address_space(1))) void*)g,
      (__attribute__((address_space(3))) void*)lds, 16, 0, 0);
}

// ---------------------------------------------------------------- GEMM
// C[M,N] = A[M,K] * B^T  where B is stored row-major [N,K] (fp16).
// Grid: (N/128, M/128, Z). Block 256 = 4 waves, each wave owns a 64x64 quadrant.
template <int EPI>  // 0: store fp16; 1: store fp32; 2: fp32 bias+relu+residual
__global__ __launch_bounds__(256) void gemm_bt(
    const u16* __restrict__ A, const u16* __restrict__ B, void* __restrict__ C,
    int K, int lda, int ldb, int ldc,
    long aZ, long bZ, long cZ,
    const float* __restrict__ bias, const float* __restrict__ xres)
{
  __shared__ u16 sA[128 * 32];
  __shared__ u16 sB[128 * 32];
  const int tid = threadIdx.x;
  const int bz = blockIdx.z;
  const u16* Ab = A + (long)bz * aZ + (long)(blockIdx.y * 128) * lda;
  const u16* Bb = B + (long)bz * bZ + (long)(blockIdx.x * 128) * ldb;

  const int lane = tid & 63;
  const int wr = (tid >> 7) & 1;
  const int wc = (tid >> 6) & 1;
  const int l15 = lane & 15, l4 = lane >> 4;

  // staging: flat f in [0,512): row=f>>2, kcol=(f&3)*8 ; LDS elem off = f*8 (linear)
  const int f0 = tid, f1 = tid + 256;
  const long ga0 = (long)(f0 >> 2) * lda + (f0 & 3) * 8;
  const long ga1 = (long)(f1 >> 2) * lda + (f1 & 3) * 8;
  const long gb0 = (long)(f0 >> 2) * ldb + (f0 & 3) * 8;
  const long gb1 = (long)(f1 >> 2) * ldb + (f1 & 3) * 8;
  u16* sAd0 = sA + (tid & ~63) * 8;          // wave-uniform LDS dest
  u16* sAd1 = sA + 2048 + (tid & ~63) * 8;
  u16* sBd0 = sB + (tid & ~63) * 8;
  u16* sBd1 = sB + 2048 + (tid & ~63) * 8;

  f32x4 acc[4][4] = {};

  for (int k0 = 0; k0 < K; k0 += 32) {
    gload_lds16(Ab + ga0 + k0, sAd0);
    gload_lds16(Ab + ga1 + k0, sAd1);
    gload_lds16(Bb + gb0 + k0, sBd0);
    gload_lds16(Bb + gb1 + k0, sBd1);
    __syncthreads();
    f16x8 af[4], bf[4];
#pragma unroll
    for (int m = 0; m < 4; ++m)
      af[m] = *(const f16x8*)(sA + (wr * 64 + m * 16 + l15) * 32 + l4 * 8);
#pragma unroll
    for (int n = 0; n < 4; ++n)
      bf[n] = *(const f16x8*)(sB + (wc * 64 + n * 16 + l15) * 32 + l4 * 8);
#pragma unroll
    for (int m = 0; m < 4; ++m)
#pragma unroll
      for (int n = 0; n < 4; ++n)
        acc[m][n] = __builtin_amdgcn_mfma_f32_16x16x32_f16(af[m], bf[n], acc[m][n], 0, 0, 0);
    __syncthreads();
  }

  const long cBase = (long)bz * cZ;
  const int rowBase = blockIdx.y * 128 + wr * 64;
  const int colBase = blockIdx.x * 128 + wc * 64;
#pragma unroll
  for (int m = 0; m < 4; ++m) {
#pragma unroll
    for (int r = 0; r < 4; ++r) {
      const long row = rowBase + m * 16 + l4 * 4 + r;
#pragma unroll
      for (int n = 0; n < 4; ++n) {
        const int col = colBase + n * 16 + l15;
        float v = acc[m][n][r];
        if constexpr (EPI == 0) {
          ((u16*)C)[cBase + row * ldc + col] = f2h(v);
        } else if constexpr (EPI == 1) {
          ((float*)C)[cBase + row * ldc + col] = v;
        } else {
          v += bias[col];
          v = fmaxf(v, 0.0f);
          v += xres[row * (long)ldc + col];
          ((float*)C)[row * (long)ldc + col] = v;
        }
      }
    }
  }
}

// ------------------------------------------------------- softmax (rows of 2048)
// Reads fp32 row, writes fp16 attn row IN-PLACE at row*4096 (u16 elems).
__global__ __launch_bounds__(256) void softmax_rows(float* __restrict__ scores)
{
  const long row = blockIdx.x;
  const float* src = scores + row * 2048;
  const int tid = threadIdx.x;
  float4 a = ((const float4*)src)[tid];
  float4 b = ((const float4*)src)[tid + 256];
  float m = fmaxf(fmaxf(fmaxf(a.x, a.y), fmaxf(a.z, a.w)),
                  fmaxf(fmaxf(b.x, b.y), fmaxf(b.z, b.w)));
#pragma unroll
  for (int o = 32; o; o >>= 1) m = fmaxf(m, __shfl_xor(m, o));
  __shared__ float redm[4];
  if ((tid & 63) == 0) redm[tid >> 6] = m;
  __syncthreads();
  m = fmaxf(fmaxf(redm[0], redm[1]), fmaxf(redm[2], redm[3]));

  float e[8];
  e[0] = __expf(a.x - m); e[1] = __expf(a.y - m);
  e[2] = __expf(a.z - m); e[3] = __expf(a.w - m);
  e[4] = __expf(b.x - m); e[5] = __expf(b.y - m);
  e[6] = __expf(b.z - m); e[7] = __expf(b.w - m);
  float s = ((e[0] + e[1]) + (e[2] + e[3])) + ((e[4] + e[5]) + (e[6] + e[7]));
#pragma unroll
  for (int o = 32; o; o >>= 1) s += __shfl_xor(s, o);
  __shared__ float reds[4];
  if ((tid & 63) == 0) reds[tid >> 6] = s;
  __syncthreads();
  s = (reds[0] + reds[1]) + (reds[2] + reds[3]);
  const float inv = 1.0f / s;

  u16* dst = (u16*)scores + row * 4096;
  uint2 w0, w1;
  w0.x = (uint32_t)f2h(e[0] * inv) | ((uint32_t)f2h(e[1] * inv) << 16);
  w0.y = (uint32_t)f2h(e[2] * inv) | ((uint32_t)f2h(e[3] * inv) << 16);
  w1.x = (uint32_t)f2h(e[4] * inv) | ((uint32_t)f2h(e[5] * inv) << 16);
  w1.y = (uint32_t)f2h(e[6] * inv) | ((uint32_t)f2h(e[7] * inv) << 16);
  ((uint2*)dst)[tid] = w0;
  ((uint2*)dst)[tid + 256] = w1;
}

// ------------------------------------------------------- layernorm (rows of 1024)
// Safe to run in-place (out == y): all reads precede writes via barriers.
__global__ __launch_bounds__(256) void layernorm_rows(
    const float* __restrict__ y, const float* __restrict__ gamma,
    const float* __restrict__ beta, float* __restrict__ out)
{
  const long row = blockIdx.x;
  const int tid = threadIdx.x;
  float4 v = ((const float4*)(y + row * 1024))[tid];
  float s = (v.x + v.y) + (v.z + v.w);
  float q = (v.x * v.x + v.y * v.y) + (v.z * v.z + v.w * v.w);
#pragma unroll
  for (int o = 32; o; o >>= 1) { s += __shfl_xor(s, o); q += __shfl_xor(q, o); }
  __shared__ float rs[4], rq[4];
  if ((tid & 63) == 0) { rs[tid >> 6] = s; rq[tid >> 6] = q; }
  __syncthreads();
  s = (rs[0] + rs[1]) + (rs[2] + rs[3]);
  q = (rq[0] + rq[1]) + (rq[2] + rq[3]);
  const float mu = s * (1.0f / 1024.0f);
  const float var = q * (1.0f / 1024.0f) - mu * mu;
  const float rstd = rsqrtf(var + 1e-5f);
  float4 g = ((const float4*)gamma)[tid];
  float4 be = ((const float4*)beta)[tid];
  float4 o;
  o.x = (v.x - mu) * rstd * g.x + be.x;
  o.y = (v.y - mu) * rstd * g.y + be.y;
  o.z = (v.z - mu) * rstd * g.z + be.z;
  o.w = (v.w - mu) * rstd * g.w + be.w;
  __syncthreads();
  ((float4*)(out + row * 1024))[tid] = o;
}

// ------------------------------------------------------- fp32 -> fp16 (flat)
__global__ __launch_bounds__(256) void cvt_f32_f16(
    const float* __restrict__ in, u16* __restrict__ out, long n4)
{
  const long stride = (long)gridDim.x * 256;
  for (long i = (long)blockIdx.x * 256 + threadIdx.x; i < n4; i += stride) {
    float4 v = ((const float4*)in)[i];
    uint2 p;
    p.x = (uint32_t)f2h(v.x) | ((uint32_t)f2h(v.y) << 16);
    p.y = (uint32_t)f2h(v.z) | ((uint32_t)f2h(v.w) << 16);
    ((uint2*)out)[i] = p;
  }
}

// ------------------------------------------------------- transpose fp32->fp16
// in [R][C] fp32 -> out [C][R] fp16.  Grid: (C/32, R/32). Block 256.
__global__ __launch_bounds__(256) void tw_f32(
    const float* __restrict__ in, u16* __restrict__ out, int R, int C)
{
  __shared__ float T[32][33];
  const int c0 = blockIdx.x * 32, r0 = blockIdx.y * 32;
  const int tx = threadIdx.x & 31, ty = threadIdx.x >> 5;  // ty 0..7
#pragma unroll
  for (int i = 0; i < 4; ++i)
    T[ty + i * 8][tx] = in[(long)(r0 + ty + i * 8) * C + c0 + tx];
  __syncthreads();
#pragma unroll
  for (int i = 0; i < 4; ++i)
    out[(long)(c0 + ty + i * 8) * R + r0 + tx] = f2h(T[tx][ty + i * 8]);
}

// ------------------------------------------------------- transpose u16 (per z)
// in [z][R][C] -> out [z][C][R].  Grid: (C/32, R/32, Z). Block 256.
__global__ __launch_bounds__(256) void transpose_u16(
    const u16* __restrict__ in, u16* __restrict__ out, int R, int C)
{
  __shared__ u16 T[32][33];
  const long zo = (long)blockIdx.z * R * C;
  const int c0 = blockIdx.x * 32, r0 = blockIdx.y * 32;
  const int tx = threadIdx.x & 31, ty = threadIdx.x >> 5;
#pragma unroll
  for (int i = 0; i < 4; ++i)
    T[ty + i * 8][tx] = in[zo + (long)(r0 + ty + i * 8) * C + c0 + tx];
  __syncthreads();
#pragma unroll
  for (int i = 0; i < 4; ++i)
    out[zo + (long)(c0 + ty + i * 8) * R + r0 + tx] = T[tx][ty + i * 8];
}

// ---------------------------------------------------------------- launch
extern "C" void kernel_launch(void* const* d_in, const int* in_sizes, int n_in,
                              void* d_out, int out_size, void* d_ws, size_t ws_size,
                              hipStream_t stream)
{
  const float* x     = (const float*)d_in[0];   // [16384,1024] (8*2048 rows)
  const float* Wq    = (const float*)d_in[1];   // [1024,2048]
  const float* Wk    = (const float*)d_in[2];
  const float* Wv    = (const float*)d_in[3];
  const float* Wfc   = (const float*)d_in[4];   // [2048,1024]
  const float* bfc   = (const float*)d_in[5];   // [1024]
  const float* gamma = (const float*)d_in[6];
  const float* beta  = (const float*)d_in[7];
  float* out = (float*)d_out;

  char* ws = (char*)d_ws;

  // Weights (both tiers): [0, 16,777,216)
  u16* wqkvT = (u16*)(ws + 0);            // 3 x [2048][1024] = 12,582,912 B
  u16* wfcT  = (u16*)(ws + 12582912);     //     [1024][2048] =  4,194,304 B
  tw_f32<<<dim3(64, 32), 256, 0, stream>>>(Wq, wqkvT, 1024, 2048);
  tw_f32<<<dim3(64, 32), 256, 0, stream>>>(Wk, wqkvT + (long)2048 * 1024, 1024, 2048);
  tw_f32<<<dim3(64, 32), 256, 0, stream>>>(Wv, wqkvT + (long)2 * 2048 * 1024, 1024, 2048);
  tw_f32<<<dim3(32, 64), 256, 0, stream>>>(Wfc, wfcT, 2048, 1024);

  if (ws_size >= 385875968ULL) {
    // ---------------- Tier A: full-batch ----------------
    u16*  xb     = (u16*)(ws + 16777216);     // 33,554,432
    u16*  qkv    = (u16*)(ws + 50331648);     // 201,326,592
    u16*  q_     = qkv;
    u16*  k_     = qkv + (long)16384 * 2048;
    u16*  v_     = qkv + (long)2 * 16384 * 2048;
    float* scores = (float*)(ws + 251658240); // 134,217,728 (also holds fp16 attn)
    u16*  vT   = k_;            // alias: k dead after scores gemm
    u16*  attx = q_;            // alias: q dead after scores gemm

    cvt_f32_f16<<<2048, 256, 0, stream>>>(x, xb, (long)16384 * 1024 / 4);

    // QKV projections: z = 0,1,2 over {Wq,Wk,Wv}
    gemm_bt<0><<<dim3(16, 128, 3), 256, 0, stream>>>(
        xb, wqkvT, (void*)qkv, 1024, 1024, 1024, 2048,
        0L, (long)2048 * 1024, (long)16384 * 2048, nullptr, nullptr);

    // scores = q @ k^T per batch (fp32)
    gemm_bt<1><<<dim3(16, 16, 8), 256, 0, stream>>>(
        q_, k_, (void*)scores, 2048, 2048, 2048, 2048,
        (long)2048 * 2048, (long)2048 * 2048, (long)2048 * 2048, nullptr, nullptr);

    // softmax rows (fp32 -> fp16 in place, attn row stride 4096)
    softmax_rows<<<16384, 256, 0, stream>>>(scores);

    // v -> vT per batch
    transpose_u16<<<dim3(64, 64, 8), 256, 0, stream>>>(v_, vT, 2048, 2048);

    // att_x = attn @ v  (attn as fp16 with lda=4096)
    gemm_bt<0><<<dim3(16, 16, 8), 256, 0, stream>>>(
        (const u16*)scores, vT, (void*)attx, 2048, 4096, 2048, 2048,
        (long)2048 * 4096, (long)2048 * 2048, (long)2048 * 2048, nullptr, nullptr);

    // d_out = x + relu(att_x @ Wfc + bfc)   (fp32)
    gemm_bt<2><<<dim3(8, 128, 1), 256, 0, stream>>>(
        attx, wfcT, (void*)out, 2048, 2048, 2048, 1024,
        0L, 0L, 0L, bfc, x);
  } else {
    // ---------------- Tier B: per-batch (needs 62,914,560 B of ws) ----------------
    u16*  xb_b   = (u16*)(ws + 16777216);     //  4,194,304
    u16*  qkv_b  = (u16*)(ws + 20971520);     // 25,165,824
    u16*  q_b    = qkv_b;
    u16*  k_b    = qkv_b + (long)2048 * 2048;
    u16*  v_b    = qkv_b + (long)2 * 2048 * 2048;
    float* sc_b  = (float*)(ws + 46137344);   // 16,777,216 (also holds fp16 attn)
    u16*  vT_b   = k_b;          // alias: k dead after scores gemm
    u16*  attx_b = q_b;          // alias: q dead after scores gemm

    for (int b = 0; b < 8; ++b) {
      const float* x_b = x + (long)b * 2048 * 1024;

      cvt_f32_f16<<<512, 256, 0, stream>>>(x_b, xb_b, (long)2048 * 1024 / 4);

      gemm_bt<0><<<dim3(16, 16, 3), 256, 0, stream>>>(
          xb_b, wqkvT, (void*)qkv_b, 1024, 1024, 1024, 2048,
          0L, (long)2048 * 1024, (long)2048 * 2048, nullptr, nullptr);

      gemm_bt<1><<<dim3(16, 16, 1), 256, 0, stream>>>(
          q_b, k_b, (void*)sc_b, 2048, 2048, 2048, 2048,
          0L, 0L, 0L, nullptr, nullptr);

      softmax_rows<<<2048, 256, 0, stream>>>(sc_b);

      transpose_u16<<<dim3(64, 64, 1), 256, 0, stream>>>(v_b, vT_b, 2048, 2048);

      gemm_bt<0><<<dim3(16, 16, 1), 256, 0, stream>>>(
          (const u16*)sc_b, vT_b, (void*)attx_b, 2048, 4096, 2048, 2048,
          0L, 0L, 0L, nullptr, nullptr);

      gemm_bt<2><<<dim3(8, 16, 1), 256, 0, stream>>>(
          attx_b, wfcT, (void*)(out + (long)b * 2048 * 1024), 2048, 2048, 2048, 1024,
          0L, 0L, 0L, bfc, x_b);
    }
  }

  // layernorm in-place on d_out
  layernorm_rows<<<16384, 256, 0, stream>>>(out, gamma, beta, out);
}

// Round 4
// 1086.795 us; speedup vs baseline: 1.4826x; 1.4826x over previous
//
#include <hip/hip_runtime.h>
#include <stdint.h>

// Fused transformer block on MI355X (gfx950), fp16 MFMA pipeline.
// Plan ladder by ws_size (host-side constant branch, graph-safe):
//  Plan A (ws >= 240 MiB): full-batch; QKV reads fp32 x directly (in-kernel cvt),
//          V written pre-transposed by epilogue; attention chunked over 512 Q-rows
//          x 8 batches with one 32MB scores buffer; attx aliases q per chunk.
//  Plan B (ws >= 104 MiB): 2 batches per iteration (z=2 grids).
//  Plan C (ws >=  60 MiB): per-batch fallback (round-3 verified).
// GEMM: m97 structure (128x128 tile, BK=32, 4 waves, global_load_lds width 16).

#define DEVI __device__ __forceinline__

typedef uint16_t u16;
typedef _Float16 f16x8 __attribute__((ext_vector_type(8)));
typedef float f32x4 __attribute__((ext_vector_type(4)));

DEVI u16 f2h(float f) {  // fp32 -> fp16 bits (RNE via v_cvt_f16_f32)
  union { _Float16 h; u16 u; } v;
  v.h = (_Float16)f;
  return v.u;
}

DEVI void gload_lds16(const void* g, void* lds) {
  __builtin_amdgcn_global_load_lds(
      (const __attribute__((address_space(1))) void*)g,
      (__attribute__((address_space(3))) void*)lds, 16, 0, 0);
}

// ---------------------------------------------------------------- GEMM
// C[M,N] = A[M,K] * B^T  where B is stored row-major [N,K] (fp16).
// Grid: (N/128, M/128, Z). Block 256 = 4 waves, each wave owns a 64x64 quadrant.
// EPI: 0 store fp16; 1 store fp32; 2 fp32 bias+relu+residual;
//      3 fp16 store transposed per 2048-row batch: vT[(row>>11)][col][row&2047]
// AF32: A is fp32 (lda in floats); converted to fp16 during LDS staging.
template <int EPI, int AF32>
__global__ __launch_bounds__(256) void gemm_bt(
    const void* __restrict__ A_, const u16* __restrict__ B, void* __restrict__ C,
    int K, int lda, int ldb, int ldc,
    long aZ, long bZ, long cZ,
    const float* __restrict__ bias, const float* __restrict__ xres)
{
  __shared__ u16 sA[128 * 32];
  __shared__ u16 sB[128 * 32];
  const int tid = threadIdx.x;
  const int bz = blockIdx.z;
  const u16* Bb = B + (long)bz * bZ + (long)(blockIdx.x * 128) * ldb;

  const int lane = tid & 63;
  const int wr = (tid >> 7) & 1;
  const int wc = (tid >> 6) & 1;
  const int l15 = lane & 15, l4 = lane >> 4;

  // B staging: flat f in [0,512): row=f>>2, kcol=(f&3)*8 ; LDS off = f*8 (linear)
  const int f0 = tid, f1 = tid + 256;
  const long gb0 = (long)(f0 >> 2) * ldb + (f0 & 3) * 8;
  const long gb1 = (long)(f1 >> 2) * ldb + (f1 & 3) * 8;
  u16* sBd0 = sB + (tid & ~63) * 8;          // wave-uniform LDS dest
  u16* sBd1 = sB + 2048 + (tid & ~63) * 8;

  // A staging (fp16 path)
  const u16* Ab16 = (const u16*)A_ + (long)bz * aZ + (long)(blockIdx.y * 128) * lda;
  const long ga0 = (long)(f0 >> 2) * lda + (f0 & 3) * 8;
  const long ga1 = (long)(f1 >> 2) * lda + (f1 & 3) * 8;
  u16* sAd0 = sA + (tid & ~63) * 8;
  u16* sAd1 = sA + 2048 + (tid & ~63) * 8;
  // A staging (fp32 path): f in [0,1024): row=f>>3, seg=f&7 (4 floats per seg)
  const float* Abf = (const float*)A_ + (long)bz * aZ + (long)(blockIdx.y * 128) * lda;

  f32x4 acc[4][4] = {};

  for (int k0 = 0; k0 < K; k0 += 32) {
    gload_lds16(Bb + gb0 + k0, sBd0);
    gload_lds16(Bb + gb1 + k0, sBd1);
    if constexpr (AF32) {
#pragma unroll
      for (int j = 0; j < 4; ++j) {
        const int f = tid + j * 256;
        const int row = f >> 3, seg = f & 7;
        float4 v = *(const float4*)(Abf + (long)row * lda + seg * 4 + k0);
        ushort4 h;
        h.x = f2h(v.x); h.y = f2h(v.y); h.z = f2h(v.z); h.w = f2h(v.w);
        *(ushort4*)(sA + row * 32 + seg * 4) = h;
      }
    } else {
      gload_lds16(Ab16 + ga0 + k0, sAd0);
      gload_lds16(Ab16 + ga1 + k0, sAd1);
    }
    __syncthreads();
    f16x8 af[4], bf[4];
#pragma unroll
    for (int m = 0; m < 4; ++m)
      af[m] = *(const f16x8*)(sA + (wr * 64 + m * 16 + l15) * 32 + l4 * 8);
#pragma unroll
    for (int n = 0; n < 4; ++n)
      bf[n] = *(const f16x8*)(sB + (wc * 64 + n * 16 + l15) * 32 + l4 * 8);
#pragma unroll
    for (int m = 0; m < 4; ++m)
#pragma unroll
      for (int n = 0; n < 4; ++n)
        acc[m][n] = __builtin_amdgcn_mfma_f32_16x16x32_f16(af[m], bf[n], acc[m][n], 0, 0, 0);
    __syncthreads();
  }

  const long cBase = (long)bz * cZ;
  const int rowBase = blockIdx.y * 128 + wr * 64;
  const int colBase = blockIdx.x * 128 + wc * 64;

  if constexpr (EPI == 3) {
    // per-2048-row-batch transposed fp16 store (4 consecutive rows pack to 8B)
    u16* vT = (u16*)C;
#pragma unroll
    for (int m = 0; m < 4; ++m) {
      const long row0 = rowBase + m * 16 + l4 * 4;
      const long bb = (row0 >> 11) * 4194304L + (row0 & 2047);
#pragma unroll
      for (int n = 0; n < 4; ++n) {
        const int col = colBase + n * 16 + l15;
        ushort4 h;
        h.x = f2h(acc[m][n][0]); h.y = f2h(acc[m][n][1]);
        h.z = f2h(acc[m][n][2]); h.w = f2h(acc[m][n][3]);
        *(ushort4*)(vT + bb + (long)col * 2048) = h;
      }
    }
  } else {
#pragma unroll
    for (int m = 0; m < 4; ++m) {
#pragma unroll
      for (int r = 0; r < 4; ++r) {
        const long row = rowBase + m * 16 + l4 * 4 + r;
#pragma unroll
        for (int n = 0; n < 4; ++n) {
          const int col = colBase + n * 16 + l15;
          float v = acc[m][n][r];
          if constexpr (EPI == 0) {
            ((u16*)C)[cBase + row * ldc + col] = f2h(v);
          } else if constexpr (EPI == 1) {
            ((float*)C)[cBase + row * ldc + col] = v;
          } else {
            v += bias[col];
            v = fmaxf(v, 0.0f);
            v += xres[row * (long)ldc + col];
            ((float*)C)[row * (long)ldc + col] = v;
          }
        }
      }
    }
  }
}

// ------------------------------------------------------- softmax (rows of 2048)
// Reads fp32 row, writes fp16 attn row IN-PLACE at row*4096 (u16 elems).
__global__ __launch_bounds__(256) void softmax_rows(float* __restrict__ scores)
{
  const long row = blockIdx.x;
  const float* src = scores + row * 2048;
  const int tid = threadIdx.x;
  float4 a = ((const float4*)src)[tid];
  float4 b = ((const float4*)src)[tid + 256];
  float m = fmaxf(fmaxf(fmaxf(a.x, a.y), fmaxf(a.z, a.w)),
                  fmaxf(fmaxf(b.x, b.y), fmaxf(b.z, b.w)));
#pragma unroll
  for (int o = 32; o; o >>= 1) m = fmaxf(m, __shfl_xor(m, o));
  __shared__ float redm[4];
  if ((tid & 63) == 0) redm[tid >> 6] = m;
  __syncthreads();
  m = fmaxf(fmaxf(redm[0], redm[1]), fmaxf(redm[2], redm[3]));

  float e[8];
  e[0] = __expf(a.x - m); e[1] = __expf(a.y - m);
  e[2] = __expf(a.z - m); e[3] = __expf(a.w - m);
  e[4] = __expf(b.x - m); e[5] = __expf(b.y - m);
  e[6] = __expf(b.z - m); e[7] = __expf(b.w - m);
  float s = ((e[0] + e[1]) + (e[2] + e[3])) + ((e[4] + e[5]) + (e[6] + e[7]));
#pragma unroll
  for (int o = 32; o; o >>= 1) s += __shfl_xor(s, o);
  __shared__ float reds[4];
  if ((tid & 63) == 0) reds[tid >> 6] = s;
  __syncthreads();
  s = (reds[0] + reds[1]) + (reds[2] + reds[3]);
  const float inv = 1.0f / s;

  u16* dst = (u16*)scores + row * 4096;
  uint2 w0, w1;
  w0.x = (uint32_t)f2h(e[0] * inv) | ((uint32_t)f2h(e[1] * inv) << 16);
  w0.y = (uint32_t)f2h(e[2] * inv) | ((uint32_t)f2h(e[3] * inv) << 16);
  w1.x = (uint32_t)f2h(e[4] * inv) | ((uint32_t)f2h(e[5] * inv) << 16);
  w1.y = (uint32_t)f2h(e[6] * inv) | ((uint32_t)f2h(e[7] * inv) << 16);
  ((uint2*)dst)[tid] = w0;
  ((uint2*)dst)[tid + 256] = w1;
}

// ------------------------------------------------------- layernorm (rows of 1024)
__global__ __launch_bounds__(256) void layernorm_rows(
    const float* __restrict__ y, const float* __restrict__ gamma,
    const float* __restrict__ beta, float* __restrict__ out)
{
  const long row = blockIdx.x;
  const int tid = threadIdx.x;
  float4 v = ((const float4*)(y + row * 1024))[tid];
  float s = (v.x + v.y) + (v.z + v.w);
  float q = (v.x * v.x + v.y * v.y) + (v.z * v.z + v.w * v.w);
#pragma unroll
  for (int o = 32; o; o >>= 1) { s += __shfl_xor(s, o); q += __shfl_xor(q, o); }
  __shared__ float rs[4], rq[4];
  if ((tid & 63) == 0) { rs[tid >> 6] = s; rq[tid >> 6] = q; }
  __syncthreads();
  s = (rs[0] + rs[1]) + (rs[2] + rs[3]);
  q = (rq[0] + rq[1]) + (rq[2] + rq[3]);
  const float mu = s * (1.0f / 1024.0f);
  const float var = q * (1.0f / 1024.0f) - mu * mu;
  const float rstd = rsqrtf(var + 1e-5f);
  float4 g = ((const float4*)gamma)[tid];
  float4 be = ((const float4*)beta)[tid];
  float4 o;
  o.x = (v.x - mu) * rstd * g.x + be.x;
  o.y = (v.y - mu) * rstd * g.y + be.y;
  o.z = (v.z - mu) * rstd * g.z + be.z;
  o.w = (v.w - mu) * rstd * g.w + be.w;
  __syncthreads();
  ((float4*)(out + row * 1024))[tid] = o;
}

// ------------------------------------------------------- fp32 -> fp16 (flat)
__global__ __launch_bounds__(256) void cvt_f32_f16(
    const float* __restrict__ in, u16* __restrict__ out, long n4)
{
  const long stride = (long)gridDim.x * 256;
  for (long i = (long)blockIdx.x * 256 + threadIdx.x; i < n4; i += stride) {
    float4 v = ((const float4*)in)[i];
    uint2 p;
    p.x = (uint32_t)f2h(v.x) | ((uint32_t)f2h(v.y) << 16);
    p.y = (uint32_t)f2h(v.z) | ((uint32_t)f2h(v.w) << 16);
    ((uint2*)out)[i] = p;
  }
}

// ------------------------------------------------------- transpose fp32->fp16
__global__ __launch_bounds__(256) void tw_f32(
    const float* __restrict__ in, u16* __restrict__ out, int R, int C)
{
  __shared__ float T[32][33];
  const int c0 = blockIdx.x * 32, r0 = blockIdx.y * 32;
  const int tx = threadIdx.x & 31, ty = threadIdx.x >> 5;
#pragma unroll
  for (int i = 0; i < 4; ++i)
    T[ty + i * 8][tx] = in[(long)(r0 + ty + i * 8) * C + c0 + tx];
  __syncthreads();
#pragma unroll
  for (int i = 0; i < 4; ++i)
    out[(long)(c0 + ty + i * 8) * R + r0 + tx] = f2h(T[tx][ty + i * 8]);
}

// ------------------------------------------------------- transpose u16 (per z)
__global__ __launch_bounds__(256) void transpose_u16(
    const u16* __restrict__ in, u16* __restrict__ out, int R, int C)
{
  __shared__ u16 T[32][33];
  const long zo = (long)blockIdx.z * R * C;
  const int c0 = blockIdx.x * 32, r0 = blockIdx.y * 32;
  const int tx = threadIdx.x & 31, ty = threadIdx.x >> 5;
#pragma unroll
  for (int i = 0; i < 4; ++i)
    T[ty + i * 8][tx] = in[zo + (long)(r0 + ty + i * 8) * C + c0 + tx];
  __syncthreads();
#pragma unroll
  for (int i = 0; i < 4; ++i)
    out[zo + (long)(c0 + ty + i * 8) * R + r0 + tx] = T[tx][ty + i * 8];
}

// ---------------------------------------------------------------- launch
extern "C" void kernel_launch(void* const* d_in, const int* in_sizes, int n_in,
                              void* d_out, int out_size, void* d_ws, size_t ws_size,
                              hipStream_t stream)
{
  const float* x     = (const float*)d_in[0];   // [16384,1024] (8*2048 rows)
  const float* Wq    = (const float*)d_in[1];   // [1024,2048]
  const float* Wk    = (const float*)d_in[2];
  const float* Wv    = (const float*)d_in[3];
  const float* Wfc   = (const float*)d_in[4];   // [2048,1024]
  const float* bfc   = (const float*)d_in[5];   // [1024]
  const float* gamma = (const float*)d_in[6];
  const float* beta  = (const float*)d_in[7];
  float* out = (float*)d_out;

  char* ws = (char*)d_ws;

  // Weights (all plans): [0, 16,777,216)
  u16* wqkvT = (u16*)(ws + 0);            // 3 x [2048][1024]
  u16* wfcT  = (u16*)(ws + 12582912);     //     [1024][2048]
  tw_f32<<<dim3(64, 32), 256, 0, stream>>>(Wq, wqkvT, 1024, 2048);
  tw_f32<<<dim3(64, 32), 256, 0, stream>>>(Wk, wqkvT + (long)2048 * 1024, 1024, 2048);
  tw_f32<<<dim3(64, 32), 256, 0, stream>>>(Wv, wqkvT + (long)2 * 2048 * 1024, 1024, 2048);
  tw_f32<<<dim3(32, 64), 256, 0, stream>>>(Wfc, wfcT, 2048, 1024);

  if (ws_size >= 251658240ULL) {
    // ---------------- Plan A: full batch, chunked attention ----------------
    u16*  q_  = (u16*)(ws + 16777216);      // [16384][2048] fp16 (later attx)
    u16*  k_  = (u16*)(ws + 83886080);      // [16384][2048] fp16
    u16*  vT  = (u16*)(ws + 150994944);     // [8][2048(dk)][2048(m)] fp16
    float* sc = (float*)(ws + 218103808);   // [8][512][2048] fp32 / fp16 attn @4096

    // QKV: q,k (z = weight 0,1); C strides place k right after q
    gemm_bt<0, 1><<<dim3(16, 128, 2), 256, 0, stream>>>(
        x, wqkvT, (void*)q_, 1024, 1024, 1024, 2048,
        0L, (long)2048 * 1024, (long)16384 * 2048, nullptr, nullptr);
    // V, written pre-transposed per batch into vT
    gemm_bt<3, 1><<<dim3(16, 128, 1), 256, 0, stream>>>(
        x, wqkvT + (long)2 * 2048 * 1024, (void*)vT, 1024, 1024, 1024, 2048,
        0L, 0L, 0L, nullptr, nullptr);

    // attention in 4 chunks of 512 Q-rows x 8 batches
    for (int c = 0; c < 4; ++c) {
      const u16* qc = q_ + (long)c * 512 * 2048;
      gemm_bt<1, 0><<<dim3(16, 4, 8), 256, 0, stream>>>(
          qc, k_, (void*)sc, 2048, 2048, 2048, 2048,
          (long)2048 * 2048, (long)2048 * 2048, (long)512 * 2048, nullptr, nullptr);
      softmax_rows<<<4096, 256, 0, stream>>>(sc);
      // PV writes attx over q's chunk-c rows (those q rows are dead now)
      gemm_bt<0, 0><<<dim3(16, 4, 8), 256, 0, stream>>>(
          (const u16*)sc, vT, (void*)(q_ + (long)c * 512 * 2048), 2048, 4096, 2048, 2048,
          (long)512 * 4096, (long)2048 * 2048, (long)2048 * 2048, nullptr, nullptr);
    }

    // d_out = x + relu(attx @ Wfc + bfc)
    gemm_bt<2, 0><<<dim3(8, 128, 1), 256, 0, stream>>>(
        q_, wfcT, (void*)out, 2048, 2048, 2048, 1024,
        0L, 0L, 0L, bfc, x);
  } else if (ws_size >= 109051904ULL) {
    // ---------------- Plan B: 2 batches per iteration ----------------
    u16*  xb2 = (u16*)(ws + 16777216);      // [2][2048][1024] fp16
    u16*  q2  = (u16*)(ws + 25165824);      // [2][2048][2048]
    u16*  k2  = q2 + (long)2 * 2048 * 2048;
    u16*  v2  = q2 + (long)4 * 2048 * 2048;
    float* sc2 = (float*)(ws + 75497472);   // [2][2048][2048] fp32
    u16*  vT2   = k2;   // alias: k dead after scores gemm
    u16*  attx2 = q2;   // alias: q dead after scores gemm

    for (int p = 0; p < 4; ++p) {
      const float* xp = x + (long)p * 4096 * 1024;
      cvt_f32_f16<<<1024, 256, 0, stream>>>(xp, xb2, (long)4096 * 1024 / 4);
      for (int b = 0; b < 2; ++b)
        gemm_bt<0, 0><<<dim3(16, 16, 3), 256, 0, stream>>>(
            xb2 + (long)b * 2048 * 1024, wqkvT, (void*)(q2 + (long)b * 2048 * 2048),
            1024, 1024, 1024, 2048,
            0L, (long)2048 * 1024, (long)2 * 2048 * 2048, nullptr, nullptr);
      gemm_bt<1, 0><<<dim3(16, 16, 2), 256, 0, stream>>>(
          q2, k2, (void*)sc2, 2048, 2048, 2048, 2048,
          (long)2048 * 2048, (long)2048 * 2048, (long)2048 * 2048, nullptr, nullptr);
      softmax_rows<<<4096, 256, 0, stream>>>(sc2);
      transpose_u16<<<dim3(64, 64, 2), 256, 0, stream>>>(v2, vT2, 2048, 2048);
      gemm_bt<0, 0><<<dim3(16, 16, 2), 256, 0, stream>>>(
          (const u16*)sc2, vT2, (void*)attx2, 2048, 4096, 2048, 2048,
          (long)2048 * 4096, (long)2048 * 2048, (long)2048 * 2048, nullptr, nullptr);
      gemm_bt<2, 0><<<dim3(8, 32, 1), 256, 0, stream>>>(
          attx2, wfcT, (void*)(out + (long)p * 4096 * 1024), 2048, 2048, 2048, 1024,
          0L, 0L, 0L, bfc, xp);
    }
  } else {
    // ---------------- Plan C: per-batch fallback (round-3 verified) ----------------
    u16*  xb_b   = (u16*)(ws + 16777216);
    u16*  qkv_b  = (u16*)(ws + 20971520);
    u16*  q_b    = qkv_b;
    u16*  k_b    = qkv_b + (long)2048 * 2048;
    u16*  v_b    = qkv_b + (long)2 * 2048 * 2048;
    float* sc_b  = (float*)(ws + 46137344);
    u16*  vT_b   = k_b;
    u16*  attx_b = q_b;

    for (int b = 0; b < 8; ++b) {
      const float* x_b = x + (long)b * 2048 * 1024;
      cvt_f32_f16<<<512, 256, 0, stream>>>(x_b, xb_b, (long)2048 * 1024 / 4);
      gemm_bt<0, 0><<<dim3(16, 16, 3), 256, 0, stream>>>(
          xb_b, wqkvT, (void*)qkv_b, 1024, 1024, 1024, 2048,
          0L, (long)2048 * 1024, (long)2048 * 2048, nullptr, nullptr);
      gemm_bt<1, 0><<<dim3(16, 16, 1), 256, 0, stream>>>(
          q_b, k_b, (void*)sc_b, 2048, 2048, 2048, 2048,
          0L, 0L, 0L, nullptr, nullptr);
      softmax_rows<<<2048, 256, 0, stream>>>(sc_b);
      transpose_u16<<<dim3(64, 64, 1), 256, 0, stream>>>(v_b, vT_b, 2048, 2048);
      gemm_bt<0, 0><<<dim3(16, 16, 1), 256, 0, stream>>>(
          (const u16*)sc_b, vT_b, (void*)attx_b, 2048, 4096, 2048, 2048,
          0L, 0L, 0L, nullptr, nullptr);
      gemm_bt<2, 0><<<dim3(8, 16, 1), 256, 0, stream>>>(
          attx_b, wfcT, (void*)(out + (long)b * 2048 * 1024), 2048, 2048, 2048, 1024,
          0L, 0L, 0L, bfc, x_b);
    }
  }

  // layernorm in-place on d_out
  layernorm_rows<<<16384, 256, 0, stream>>>(out, gamma, beta, out);
}

// Round 5
// 1003.935 us; speedup vs baseline: 1.6049x; 1.0825x over previous
//
#include <hip/hip_runtime.h>
#include <stdint.h>

// Fused transformer block on MI355X (gfx950), fp16 MFMA pipeline.
// Plan ladder by ws_size (host-side constant branch, graph-safe):
//  Plan A (ws >= 240 MiB): full-batch; x pre-converted to fp16 into a buffer
//          aliased with the scores chunk buffer (identical 32 MiB, disjoint
//          live ranges); V written pre-transposed by the QKV epilogue;
//          attention chunked over 512 Q-rows x 8 batches; attx aliases q.
//  Plan B (ws >= 104 MiB): 2 batches per iteration.
//  Plan C (ws >=  60 MiB): per-batch fallback (round-3 verified).
// GEMM: m97 structure (128x128 tile, BK=32, 4 waves, global_load_lds width 16)
// for BOTH operands -- no in-kernel fp32 staging (that was round-4's VALU tax).

#define DEVI __device__ __forceinline__

typedef uint16_t u16;
typedef _Float16 f16x8 __attribute__((ext_vector_type(8)));
typedef float f32x4 __attribute__((ext_vector_type(4)));

DEVI u16 f2h(float f) {  // fp32 -> fp16 bits (RNE via v_cvt_f16_f32)
  union { _Float16 h; u16 u; } v;
  v.h = (_Float16)f;
  return v.u;
}

DEVI void gload_lds16(const void* g, void* lds) {
  __builtin_amdgcn_global_load_lds(
      (const __attribute__((address_space(1))) void*)g,
      (__attribute__((address_space(3))) void*)lds, 16, 0, 0);
}

// ---------------------------------------------------------------- GEMM
// C[M,N] = A[M,K] * B^T  where B is stored row-major [N,K] (fp16).
// Grid: (N/128, M/128, Z). Block 256 = 4 waves, each wave owns a 64x64 quadrant.
// EPI: 0 store fp16; 1 store fp32; 2 fp32 bias+relu+residual;
//      3 fp16 store transposed per 2048-row batch: vT[(row>>11)][col][row&2047]
template <int EPI>
__global__ __launch_bounds__(256) void gemm_bt(
    const u16* __restrict__ A, const u16* __restrict__ B, void* __restrict__ C,
    int K, int lda, int ldb, int ldc,
    long aZ, long bZ, long cZ,
    const float* __restrict__ bias, const float* __restrict__ xres)
{
  __shared__ u16 sA[128 * 32];
  __shared__ u16 sB[128 * 32];
  const int tid = threadIdx.x;
  const int bz = blockIdx.z;
  const u16* Ab = A + (long)bz * aZ + (long)(blockIdx.y * 128) * lda;
  const u16* Bb = B + (long)bz * bZ + (long)(blockIdx.x * 128) * ldb;

  const int lane = tid & 63;
  const int wr = (tid >> 7) & 1;
  const int wc = (tid >> 6) & 1;
  const int l15 = lane & 15, l4 = lane >> 4;

  // staging: flat f in [0,512): row=f>>2, kcol=(f&3)*8 ; LDS elem off = f*8 (linear)
  const int f0 = tid, f1 = tid + 256;
  const long ga0 = (long)(f0 >> 2) * lda + (f0 & 3) * 8;
  const long ga1 = (long)(f1 >> 2) * lda + (f1 & 3) * 8;
  const long gb0 = (long)(f0 >> 2) * ldb + (f0 & 3) * 8;
  const long gb1 = (long)(f1 >> 2) * ldb + (f1 & 3) * 8;
  u16* sAd0 = sA + (tid & ~63) * 8;          // wave-uniform LDS dest
  u16* sAd1 = sA + 2048 + (tid & ~63) * 8;
  u16* sBd0 = sB + (tid & ~63) * 8;
  u16* sBd1 = sB + 2048 + (tid & ~63) * 8;

  f32x4 acc[4][4] = {};

  for (int k0 = 0; k0 < K; k0 += 32) {
    gload_lds16(Ab + ga0 + k0, sAd0);
    gload_lds16(Ab + ga1 + k0, sAd1);
    gload_lds16(Bb + gb0 + k0, sBd0);
    gload_lds16(Bb + gb1 + k0, sBd1);
    __syncthreads();
    f16x8 af[4], bf[4];
#pragma unroll
    for (int m = 0; m < 4; ++m)
      af[m] = *(const f16x8*)(sA + (wr * 64 + m * 16 + l15) * 32 + l4 * 8);
#pragma unroll
    for (int n = 0; n < 4; ++n)
      bf[n] = *(const f16x8*)(sB + (wc * 64 + n * 16 + l15) * 32 + l4 * 8);
#pragma unroll
    for (int m = 0; m < 4; ++m)
#pragma unroll
      for (int n = 0; n < 4; ++n)
        acc[m][n] = __builtin_amdgcn_mfma_f32_16x16x32_f16(af[m], bf[n], acc[m][n], 0, 0, 0);
    __syncthreads();
  }

  const long cBase = (long)bz * cZ;
  const int rowBase = blockIdx.y * 128 + wr * 64;
  const int colBase = blockIdx.x * 128 + wc * 64;

  if constexpr (EPI == 3) {
    // per-2048-row-batch transposed fp16 store (4 consecutive rows pack to 8B)
    u16* vT = (u16*)C;
#pragma unroll
    for (int m = 0; m < 4; ++m) {
      const long row0 = rowBase + m * 16 + l4 * 4;
      const long bb = (row0 >> 11) * 4194304L + (row0 & 2047);
#pragma unroll
      for (int n = 0; n < 4; ++n) {
        const int col = colBase + n * 16 + l15;
        ushort4 h;
        h.x = f2h(acc[m][n][0]); h.y = f2h(acc[m][n][1]);
        h.z = f2h(acc[m][n][2]); h.w = f2h(acc[m][n][3]);
        *(ushort4*)(vT + bb + (long)col * 2048) = h;
      }
    }
  } else {
#pragma unroll
    for (int m = 0; m < 4; ++m) {
#pragma unroll
      for (int r = 0; r < 4; ++r) {
        const long row = rowBase + m * 16 + l4 * 4 + r;
#pragma unroll
        for (int n = 0; n < 4; ++n) {
          const int col = colBase + n * 16 + l15;
          float v = acc[m][n][r];
          if constexpr (EPI == 0) {
            ((u16*)C)[cBase + row * ldc + col] = f2h(v);
          } else if constexpr (EPI == 1) {
            ((float*)C)[cBase + row * ldc + col] = v;
          } else {
            v += bias[col];
            v = fmaxf(v, 0.0f);
            v += xres[row * (long)ldc + col];
            ((float*)C)[row * (long)ldc + col] = v;
          }
        }
      }
    }
  }
}

// ------------------------------------------------------- softmax (rows of 2048)
// Reads fp32 row, writes fp16 attn row IN-PLACE at row*4096 (u16 elems).
__global__ __launch_bounds__(256) void softmax_rows(float* __restrict__ scores)
{
  const long row = blockIdx.x;
  const float* src = scores + row * 2048;
  const int tid = threadIdx.x;
  float4 a = ((const float4*)src)[tid];
  float4 b = ((const float4*)src)[tid + 256];
  float m = fmaxf(fmaxf(fmaxf(a.x, a.y), fmaxf(a.z, a.w)),
                  fmaxf(fmaxf(b.x, b.y), fmaxf(b.z, b.w)));
#pragma unroll
  for (int o = 32; o; o >>= 1) m = fmaxf(m, __shfl_xor(m, o));
  __shared__ float redm[4];
  if ((tid & 63) == 0) redm[tid >> 6] = m;
  __syncthreads();
  m = fmaxf(fmaxf(redm[0], redm[1]), fmaxf(redm[2], redm[3]));

  float e[8];
  e[0] = __expf(a.x - m); e[1] = __expf(a.y - m);
  e[2] = __expf(a.z - m); e[3] = __expf(a.w - m);
  e[4] = __expf(b.x - m); e[5] = __expf(b.y - m);
  e[6] = __expf(b.z - m); e[7] = __expf(b.w - m);
  float s = ((e[0] + e[1]) + (e[2] + e[3])) + ((e[4] + e[5]) + (e[6] + e[7]));
#pragma unroll
  for (int o = 32; o; o >>= 1) s += __shfl_xor(s, o);
  __shared__ float reds[4];
  if ((tid & 63) == 0) reds[tid >> 6] = s;
  __syncthreads();
  s = (reds[0] + reds[1]) + (reds[2] + reds[3]);
  const float inv = 1.0f / s;

  u16* dst = (u16*)scores + row * 4096;
  uint2 w0, w1;
  w0.x = (uint32_t)f2h(e[0] * inv) | ((uint32_t)f2h(e[1] * inv) << 16);
  w0.y = (uint32_t)f2h(e[2] * inv) | ((uint32_t)f2h(e[3] * inv) << 16);
  w1.x = (uint32_t)f2h(e[4] * inv) | ((uint32_t)f2h(e[5] * inv) << 16);
  w1.y = (uint32_t)f2h(e[6] * inv) | ((uint32_t)f2h(e[7] * inv) << 16);
  ((uint2*)dst)[tid] = w0;
  ((uint2*)dst)[tid + 256] = w1;
}

// ------------------------------------------------------- layernorm (rows of 1024)
__global__ __launch_bounds__(256) void layernorm_rows(
    const float* __restrict__ y, const float* __restrict__ gamma,
    const float* __restrict__ beta, float* __restrict__ out)
{
  const long row = blockIdx.x;
  const int tid = threadIdx.x;
  float4 v = ((const float4*)(y + row * 1024))[tid];
  float s = (v.x + v.y) + (v.z + v.w);
  float q = (v.x * v.x + v.y * v.y) + (v.z * v.z + v.w * v.w);
#pragma unroll
  for (int o = 32; o; o >>= 1) { s += __shfl_xor(s, o); q += __shfl_xor(q, o); }
  __shared__ float rs[4], rq[4];
  if ((tid & 63) == 0) { rs[tid >> 6] = s; rq[tid >> 6] = q; }
  __syncthreads();
  s = (rs[0] + rs[1]) + (rs[2] + rs[3]);
  q = (rq[0] + rq[1]) + (rq[2] + rq[3]);
  const float mu = s * (1.0f / 1024.0f);
  const float var = q * (1.0f / 1024.0f) - mu * mu;
  const float rstd = rsqrtf(var + 1e-5f);
  float4 g = ((const float4*)gamma)[tid];
  float4 be = ((const float4*)beta)[tid];
  float4 o;
  o.x = (v.x - mu) * rstd * g.x + be.x;
  o.y = (v.y - mu) * rstd * g.y + be.y;
  o.z = (v.z - mu) * rstd * g.z + be.z;
  o.w = (v.w - mu) * rstd * g.w + be.w;
  __syncthreads();
  ((float4*)(out + row * 1024))[tid] = o;
}

// ------------------------------------------------------- fp32 -> fp16 (flat)
__global__ __launch_bounds__(256) void cvt_f32_f16(
    const float* __restrict__ in, u16* __restrict__ out, long n4)
{
  const long stride = (long)gridDim.x * 256;
  for (long i = (long)blockIdx.x * 256 + threadIdx.x; i < n4; i += stride) {
    float4 v = ((const float4*)in)[i];
    uint2 p;
    p.x = (uint32_t)f2h(v.x) | ((uint32_t)f2h(v.y) << 16);
    p.y = (uint32_t)f2h(v.z) | ((uint32_t)f2h(v.w) << 16);
    ((uint2*)out)[i] = p;
  }
}

// ------------------------------------------------------- transpose fp32->fp16
__global__ __launch_bounds__(256) void tw_f32(
    const float* __restrict__ in, u16* __restrict__ out, int R, int C)
{
  __shared__ float T[32][33];
  const int c0 = blockIdx.x * 32, r0 = blockIdx.y * 32;
  const int tx = threadIdx.x & 31, ty = threadIdx.x >> 5;
#pragma unroll
  for (int i = 0; i < 4; ++i)
    T[ty + i * 8][tx] = in[(long)(r0 + ty + i * 8) * C + c0 + tx];
  __syncthreads();
#pragma unroll
  for (int i = 0; i < 4; ++i)
    out[(long)(c0 + ty + i * 8) * R + r0 + tx] = f2h(T[tx][ty + i * 8]);
}

// ------------------------------------------------------- transpose u16 (per z)
__global__ __launch_bounds__(256) void transpose_u16(
    const u16* __restrict__ in, u16* __restrict__ out, int R, int C)
{
  __shared__ u16 T[32][33];
  const long zo = (long)blockIdx.z * R * C;
  const int c0 = blockIdx.x * 32, r0 = blockIdx.y * 32;
  const int tx = threadIdx.x & 31, ty = threadIdx.x >> 5;
#pragma unroll
  for (int i = 0; i < 4; ++i)
    T[ty + i * 8][tx] = in[zo + (long)(r0 + ty + i * 8) * C + c0 + tx];
  __syncthreads();
#pragma unroll
  for (int i = 0; i < 4; ++i)
    out[zo + (long)(c0 + ty + i * 8) * R + r0 + tx] = T[tx][ty + i * 8];
}

// ---------------------------------------------------------------- launch
extern "C" void kernel_launch(void* const* d_in, const int* in_sizes, int n_in,
                              void* d_out, int out_size, void* d_ws, size_t ws_size,
                              hipStream_t stream)
{
  const float* x     = (const float*)d_in[0];   // [16384,1024] (8*2048 rows)
  const float* Wq    = (const float*)d_in[1];   // [1024,2048]
  const float* Wk    = (const float*)d_in[2];
  const float* Wv    = (const float*)d_in[3];
  const float* Wfc   = (const float*)d_in[4];   // [2048,1024]
  const float* bfc   = (const float*)d_in[5];   // [1024]
  const float* gamma = (const float*)d_in[6];
  const float* beta  = (const float*)d_in[7];
  float* out = (float*)d_out;

  char* ws = (char*)d_ws;

  // Weights (all plans): [0, 16,777,216)
  u16* wqkvT = (u16*)(ws + 0);            // 3 x [2048][1024]
  u16* wfcT  = (u16*)(ws + 12582912);     //     [1024][2048]
  tw_f32<<<dim3(64, 32), 256, 0, stream>>>(Wq, wqkvT, 1024, 2048);
  tw_f32<<<dim3(64, 32), 256, 0, stream>>>(Wk, wqkvT + (long)2048 * 1024, 1024, 2048);
  tw_f32<<<dim3(64, 32), 256, 0, stream>>>(Wv, wqkvT + (long)2 * 2048 * 1024, 1024, 2048);
  tw_f32<<<dim3(32, 64), 256, 0, stream>>>(Wfc, wfcT, 2048, 1024);

  if (ws_size >= 251658240ULL) {
    // ---------------- Plan A: full batch, chunked attention ----------------
    u16*  q_  = (u16*)(ws + 16777216);      // [16384][2048] fp16 (later attx)
    u16*  k_  = (u16*)(ws + 83886080);      // [16384][2048] fp16
    u16*  vT  = (u16*)(ws + 150994944);     // [8][2048(dk)][2048(m)] fp16
    float* sc = (float*)(ws + 218103808);   // 32 MiB: scores chunks (fp32/fp16@4096)
    u16*  xb  = (u16*)sc;                   // ALIAS: xb (32 MiB) dies before sc born

    // x -> fp16 once (removes round-4's in-GEMM fp32 staging VALU tax)
    cvt_f32_f16<<<2048, 256, 0, stream>>>(x, xb, (long)16384 * 1024 / 4);

    // QKV: q,k (z = weight 0,1)
    gemm_bt<0><<<dim3(16, 128, 2), 256, 0, stream>>>(
        xb, wqkvT, (void*)q_, 1024, 1024, 1024, 2048,
        0L, (long)2048 * 1024, (long)16384 * 2048, nullptr, nullptr);
    // V, written pre-transposed per batch into vT
    gemm_bt<3><<<dim3(16, 128, 1), 256, 0, stream>>>(
        xb, wqkvT + (long)2 * 2048 * 1024, (void*)vT, 1024, 1024, 1024, 2048,
        0L, 0L, 0L, nullptr, nullptr);

    // attention in 4 chunks of 512 Q-rows x 8 batches (xb dead from here on)
    for (int c = 0; c < 4; ++c) {
      const u16* qc = q_ + (long)c * 512 * 2048;
      gemm_bt<1><<<dim3(16, 4, 8), 256, 0, stream>>>(
          qc, k_, (void*)sc, 2048, 2048, 2048, 2048,
          (long)2048 * 2048, (long)2048 * 2048, (long)512 * 2048, nullptr, nullptr);
      softmax_rows<<<4096, 256, 0, stream>>>(sc);
      // PV writes attx over q's chunk-c rows (those q rows are dead now)
      gemm_bt<0><<<dim3(16, 4, 8), 256, 0, stream>>>(
          (const u16*)sc, vT, (void*)(q_ + (long)c * 512 * 2048), 2048, 4096, 2048, 2048,
          (long)512 * 4096, (long)2048 * 2048, (long)2048 * 2048, nullptr, nullptr);
    }

    // d_out = x + relu(attx @ Wfc + bfc)
    gemm_bt<2><<<dim3(8, 128, 1), 256, 0, stream>>>(
        q_, wfcT, (void*)out, 2048, 2048, 2048, 1024,
        0L, 0L, 0L, bfc, x);
  } else if (ws_size >= 109051904ULL) {
    // ---------------- Plan B: 2 batches per iteration ----------------
    u16*  xb2 = (u16*)(ws + 16777216);      // [2][2048][1024] fp16
    u16*  q2  = (u16*)(ws + 25165824);      // [2][2048][2048]
    u16*  k2  = q2 + (long)2 * 2048 * 2048;
    u16*  v2  = q2 + (long)4 * 2048 * 2048;
    float* sc2 = (float*)(ws + 75497472);   // [2][2048][2048] fp32
    u16*  vT2   = k2;   // alias: k dead after scores gemm
    u16*  attx2 = q2;   // alias: q dead after scores gemm

    for (int p = 0; p < 4; ++p) {
      const float* xp = x + (long)p * 4096 * 1024;
      cvt_f32_f16<<<1024, 256, 0, stream>>>(xp, xb2, (long)4096 * 1024 / 4);
      for (int b = 0; b < 2; ++b)
        gemm_bt<0><<<dim3(16, 16, 3), 256, 0, stream>>>(
            xb2 + (long)b * 2048 * 1024, wqkvT, (void*)(q2 + (long)b * 2048 * 2048),
            1024, 1024, 1024, 2048,
            0L, (long)2048 * 1024, (long)2 * 2048 * 2048, nullptr, nullptr);
      gemm_bt<1><<<dim3(16, 16, 2), 256, 0, stream>>>(
          q2, k2, (void*)sc2, 2048, 2048, 2048, 2048,
          (long)2048 * 2048, (long)2048 * 2048, (long)2048 * 2048, nullptr, nullptr);
      softmax_rows<<<4096, 256, 0, stream>>>(sc2);
      transpose_u16<<<dim3(64, 64, 2), 256, 0, stream>>>(v2, vT2, 2048, 2048);
      gemm_bt<0><<<dim3(16, 16, 2), 256, 0, stream>>>(
          (const u16*)sc2, vT2, (void*)attx2, 2048, 4096, 2048, 2048,
          (long)2048 * 4096, (long)2048 * 2048, (long)2048 * 2048, nullptr, nullptr);
      gemm_bt<2><<<dim3(8, 32, 1), 256, 0, stream>>>(
          attx2, wfcT, (void*)(out + (long)p * 4096 * 1024), 2048, 2048, 2048, 1024,
          0L, 0L, 0L, bfc, xp);
    }
  } else {
    // ---------------- Plan C: per-batch fallback (round-3 verified) ----------------
    u16*  xb_b   = (u16*)(ws + 16777216);
    u16*  qkv_b  = (u16*)(ws + 20971520);
    u16*  q_b    = qkv_b;
    u16*  k_b    = qkv_b + (long)2048 * 2048;
    u16*  v_b    = qkv_b + (long)2 * 2048 * 2048;
    float* sc_b  = (float*)(ws + 46137344);
    u16*  vT_b   = k_b;
    u16*  attx_b = q_b;

    for (int b = 0; b < 8; ++b) {
      const float* x_b = x + (long)b * 2048 * 1024;
      cvt_f32_f16<<<512, 256, 0, stream>>>(x_b, xb_b, (long)2048 * 1024 / 4);
      gemm_bt<0><<<dim3(16, 16, 3), 256, 0, stream>>>(
          xb_b, wqkvT, (void*)qkv_b, 1024, 1024, 1024, 2048,
          0L, (long)2048 * 1024, (long)2048 * 2048, nullptr, nullptr);
      gemm_bt<1><<<dim3(16, 16, 1), 256, 0, stream>>>(
          q_b, k_b, (void*)sc_b, 2048, 2048, 2048, 2048,
          0L, 0L, 0L, nullptr, nullptr);
      softmax_rows<<<2048, 256, 0, stream>>>(sc_b);
      transpose_u16<<<dim3(64, 64, 1), 256, 0, stream>>>(v_b, vT_b, 2048, 2048);
      gemm_bt<0><<<dim3(16, 16, 1), 256, 0, stream>>>(
          (const u16*)sc_b, vT_b, (void*)attx_b, 2048, 4096, 2048, 2048,
          0L, 0L, 0L, nullptr, nullptr);
      gemm_bt<2><<<dim3(8, 16, 1), 256, 0, stream>>>(
          attx_b, wfcT, (void*)(out + (long)b * 2048 * 1024), 2048, 2048, 2048, 1024,
          0L, 0L, 0L, bfc, x_b);
    }
  }

  // layernorm in-place on d_out
  layernorm_rows<<<16384, 256, 0, stream>>>(out, gamma, beta, out);
}

// Round 6
// 710.177 us; speedup vs baseline: 2.2688x; 1.4136x over previous
//
#include <hip/hip_runtime.h>
#include <stdint.h>

// Fused transformer block on MI355X (gfx950), fp16 MFMA pipeline.
// Plan A (ws >= 240 MiB) now uses gemm256: 256x128 tile, BK=64, 8 waves,
//   3-buffer LDS pipeline (prefetch distance 2), counted s_waitcnt vmcnt(6),
//   raw s_barrier (1 per K-tile), setprio around 32-MFMA cluster, and
//   XOR bank swizzle (byte ^= (row&7)<<4) via inverse-swizzled global source
//   + swizzled ds_read (both-sides-or-neither).
// Plans B/C keep the round-3-verified m97-structure gemm_bt.

#define DEVI __device__ __forceinline__

typedef uint16_t u16;
typedef _Float16 f16x8 __attribute__((ext_vector_type(8)));
typedef float f32x4 __attribute__((ext_vector_type(4)));

DEVI u16 f2h(float f) {
  union { _Float16 h; u16 u; } v;
  v.h = (_Float16)f;
  return v.u;
}

DEVI void gload_lds16(const void* g, void* lds) {
  __builtin_amdgcn_global_load_lds(
      (const __attribute__((address_space(1))) void*)g,
      (__attribute__((address_space(3))) void*)lds, 16, 0, 0);
}

// ================================================================ gemm256
// C[M,N] = A[M,K] * B^T, B row-major [N,K] (fp16), 512 threads = 8 waves.
// Tile 256(M) x 128(N), BK=64. Wave (wm=wid>>1 in [0,4), wn=wid&1 in [0,2))
// owns 64x64 via 4x4 16x16x32 fragments. LDS: 3 bufs x (A 32KB + B 16KB).
// EPI: 0 fp16; 1 fp32; 2 fp32 bias+relu+residual; 3 fp16 V-transposed store.
template <int EPI>
__global__ __launch_bounds__(512, 2) void gemm256(
    const u16* __restrict__ A, const u16* __restrict__ B, void* __restrict__ C,
    int K, int lda, int ldb, int ldc,
    long aZ, long bZ, long cZ,
    const float* __restrict__ bias, const float* __restrict__ xres)
{
  __shared__ u16 lds[3 * 24576];  // 147456 B
  char* ldsB = (char*)lds;
  const int tid = threadIdx.x;
  const int bz = blockIdx.z;

  // XCD-aware swizzle (all grids have nwg % 8 == 0)
  const int gx = gridDim.x;
  int fl = blockIdx.y * gx + blockIdx.x;
  const int cpx = (gx * gridDim.y) >> 3;
  fl = (fl & 7) * cpx + (fl >> 3);
  const int bx = fl % gx, by = fl / gx;

  const u16* Ab = A + (long)bz * aZ + (long)(by * 256) * lda;
  const u16* Bb = B + (long)bz * bZ + (long)(bx * 128) * ldb;

  // Staging source offsets (bytes): physical LDS byte d -> logical byte
  // dl = d ^ (((d>>7)&7)<<4); element at global (row=dl>>7, colbyte=dl&127).
  long aoff[4], boff[2];
#pragma unroll
  for (int r = 0; r < 4; ++r) {
    const int d = tid * 16 + r * 8192;
    const int dl = d ^ (((d >> 7) & 7) << 4);
    aoff[r] = (long)(dl >> 7) * (lda * 2) + (dl & 127);
  }
#pragma unroll
  for (int r = 0; r < 2; ++r) {
    const int d = tid * 16 + r * 8192;
    const int dl = d ^ (((d >> 7) & 7) << 4);
    boff[r] = (long)(dl >> 7) * (ldb * 2) + (dl & 127);
  }

  const int wid = tid >> 6, lane = tid & 63;
  const int wm = wid >> 1, wn = wid & 1;
  const int l15 = lane & 15;
  const int swzm = (lane & 7) << 4;           // == (row&7)<<4 since row&7 == lane&7
  const int ko0 = ((lane >> 4) * 16) ^ swzm;  // k-sub 0 byte offset (swizzled)
  const int ko1 = (64 + (lane >> 4) * 16) ^ swzm;
  const int stgD = wid * 1024;                // wave-uniform stage dest base

  f32x4 acc[4][4] = {};

  auto STAGE = [&](int t) {
    char* ab = ldsB + (t % 3) * 49152;
    char* bb = ab + 32768;
    const long kB = (long)t * 128;  // 64 elems * 2B
#pragma unroll
    for (int r = 0; r < 4; ++r)
      gload_lds16((const char*)Ab + aoff[r] + kB, ab + stgD + r * 8192);
#pragma unroll
    for (int r = 0; r < 2; ++r)
      gload_lds16((const char*)Bb + boff[r] + kB, bb + stgD + r * 8192);
  };

  const int NT = K >> 6;
  STAGE(0);
  STAGE(1);

  for (int t = 0; t < NT; ++t) {
    if (t + 1 < NT) {
      asm volatile("s_waitcnt vmcnt(6)" ::: "memory");  // tile t landed (t+1 in flight)
    } else {
      asm volatile("s_waitcnt vmcnt(0)" ::: "memory");  // drain for last tile
    }
    __builtin_amdgcn_s_barrier();
    if (t + 2 < NT) STAGE(t + 2);

    const char* ab = ldsB + (t % 3) * 49152;
    const char* bb = ab + 32768;
#pragma unroll
    for (int ks = 0; ks < 2; ++ks) {
      const int ko = ks ? ko1 : ko0;
      f16x8 af[4], bf[4];
#pragma unroll
      for (int m = 0; m < 4; ++m)
        af[m] = *(const f16x8*)(ab + (wm * 64 + m * 16 + l15) * 128 + ko);
#pragma unroll
      for (int n = 0; n < 4; ++n)
        bf[n] = *(const f16x8*)(bb + (wn * 64 + n * 16 + l15) * 128 + ko);
      __builtin_amdgcn_s_setprio(1);
#pragma unroll
      for (int m = 0; m < 4; ++m)
#pragma unroll
        for (int n = 0; n < 4; ++n)
          acc[m][n] = __builtin_amdgcn_mfma_f32_16x16x32_f16(af[m], bf[n], acc[m][n], 0, 0, 0);
      __builtin_amdgcn_s_setprio(0);
    }
  }

  const long cBase = (long)bz * cZ;
  const int rowBase = by * 256 + wm * 64;
  const int colBase = bx * 128 + wn * 64;

  if constexpr (EPI == 3) {
    u16* vT = (u16*)C;
#pragma unroll
    for (int m = 0; m < 4; ++m) {
      const long row0 = rowBase + m * 16 + (lane >> 4) * 4;
      const long bb2 = (row0 >> 11) * 4194304L + (row0 & 2047);
#pragma unroll
      for (int n = 0; n < 4; ++n) {
        const int col = colBase + n * 16 + l15;
        ushort4 h;
        h.x = f2h(acc[m][n][0]); h.y = f2h(acc[m][n][1]);
        h.z = f2h(acc[m][n][2]); h.w = f2h(acc[m][n][3]);
        *(ushort4*)(vT + bb2 + (long)col * 2048) = h;
      }
    }
  } else {
#pragma unroll
    for (int m = 0; m < 4; ++m) {
#pragma unroll
      for (int r = 0; r < 4; ++r) {
        const long row = rowBase + m * 16 + (lane >> 4) * 4 + r;
#pragma unroll
        for (int n = 0; n < 4; ++n) {
          const int col = colBase + n * 16 + l15;
          float v = acc[m][n][r];
          if constexpr (EPI == 0) {
            ((u16*)C)[cBase + row * ldc + col] = f2h(v);
          } else if constexpr (EPI == 1) {
            ((float*)C)[cBase + row * ldc + col] = v;
          } else {
            v += bias[col];
            v = fmaxf(v, 0.0f);
            v += xres[row * (long)ldc + col];
            ((float*)C)[row * (long)ldc + col] = v;
          }
        }
      }
    }
  }
}

// ================================================================ gemm_bt
// m97-structure 128x128 GEMM (Plans B/C fallback; round-3 verified).
template <int EPI>
__global__ __launch_bounds__(256) void gemm_bt(
    const u16* __restrict__ A, const u16* __restrict__ B, void* __restrict__ C,
    int K, int lda, int ldb, int ldc,
    long aZ, long bZ, long cZ,
    const float* __restrict__ bias, const float* __restrict__ xres)
{
  __shared__ u16 sA[128 * 32];
  __shared__ u16 sB[128 * 32];
  const int tid = threadIdx.x;
  const int bz = blockIdx.z;
  const u16* Ab = A + (long)bz * aZ + (long)(blockIdx.y * 128) * lda;
  const u16* Bb = B + (long)bz * bZ + (long)(blockIdx.x * 128) * ldb;

  const int lane = tid & 63;
  const int wr = (tid >> 7) & 1;
  const int wc = (tid >> 6) & 1;
  const int l15 = lane & 15, l4 = lane >> 4;

  const int f0 = tid, f1 = tid + 256;
  const long ga0 = (long)(f0 >> 2) * lda + (f0 & 3) * 8;
  const long ga1 = (long)(f1 >> 2) * lda + (f1 & 3) * 8;
  const long gb0 = (long)(f0 >> 2) * ldb + (f0 & 3) * 8;
  const long gb1 = (long)(f1 >> 2) * ldb + (f1 & 3) * 8;
  u16* sAd0 = sA + (tid & ~63) * 8;
  u16* sAd1 = sA + 2048 + (tid & ~63) * 8;
  u16* sBd0 = sB + (tid & ~63) * 8;
  u16* sBd1 = sB + 2048 + (tid & ~63) * 8;

  f32x4 acc[4][4] = {};

  for (int k0 = 0; k0 < K; k0 += 32) {
    gload_lds16(Ab + ga0 + k0, sAd0);
    gload_lds16(Ab + ga1 + k0, sAd1);
    gload_lds16(Bb + gb0 + k0, sBd0);
    gload_lds16(Bb + gb1 + k0, sBd1);
    __syncthreads();
    f16x8 af[4], bf[4];
#pragma unroll
    for (int m = 0; m < 4; ++m)
      af[m] = *(const f16x8*)(sA + (wr * 64 + m * 16 + l15) * 32 + l4 * 8);
#pragma unroll
    for (int n = 0; n < 4; ++n)
      bf[n] = *(const f16x8*)(sB + (wc * 64 + n * 16 + l15) * 32 + l4 * 8);
#pragma unroll
    for (int m = 0; m < 4; ++m)
#pragma unroll
      for (int n = 0; n < 4; ++n)
        acc[m][n] = __builtin_amdgcn_mfma_f32_16x16x32_f16(af[m], bf[n], acc[m][n], 0, 0, 0);
    __syncthreads();
  }

  const long cBase = (long)bz * cZ;
  const int rowBase = blockIdx.y * 128 + wr * 64;
  const int colBase = blockIdx.x * 128 + wc * 64;

  if constexpr (EPI == 3) {
    u16* vT = (u16*)C;
#pragma unroll
    for (int m = 0; m < 4; ++m) {
      const long row0 = rowBase + m * 16 + l4 * 4;
      const long bb = (row0 >> 11) * 4194304L + (row0 & 2047);
#pragma unroll
      for (int n = 0; n < 4; ++n) {
        const int col = colBase + n * 16 + l15;
        ushort4 h;
        h.x = f2h(acc[m][n][0]); h.y = f2h(acc[m][n][1]);
        h.z = f2h(acc[m][n][2]); h.w = f2h(acc[m][n][3]);
        *(ushort4*)(vT + bb + (long)col * 2048) = h;
      }
    }
  } else {
#pragma unroll
    for (int m = 0; m < 4; ++m) {
#pragma unroll
      for (int r = 0; r < 4; ++r) {
        const long row = rowBase + m * 16 + l4 * 4 + r;
#pragma unroll
        for (int n = 0; n < 4; ++n) {
          const int col = colBase + n * 16 + l15;
          float v = acc[m][n][r];
          if constexpr (EPI == 0) {
            ((u16*)C)[cBase + row * ldc + col] = f2h(v);
          } else if constexpr (EPI == 1) {
            ((float*)C)[cBase + row * ldc + col] = v;
          } else {
            v += bias[col];
            v = fmaxf(v, 0.0f);
            v += xres[row * (long)ldc + col];
            ((float*)C)[row * (long)ldc + col] = v;
          }
        }
      }
    }
  }
}

// ------------------------------------------------------- softmax (rows of 2048)
__global__ __launch_bounds__(256) void softmax_rows(float* __restrict__ scores)
{
  const long row = blockIdx.x;
  const float* src = scores + row * 2048;
  const int tid = threadIdx.x;
  float4 a = ((const float4*)src)[tid];
  float4 b = ((const float4*)src)[tid + 256];
  float m = fmaxf(fmaxf(fmaxf(a.x, a.y), fmaxf(a.z, a.w)),
                  fmaxf(fmaxf(b.x, b.y), fmaxf(b.z, b.w)));
#pragma unroll
  for (int o = 32; o; o >>= 1) m = fmaxf(m, __shfl_xor(m, o));
  __shared__ float redm[4];
  if ((tid & 63) == 0) redm[tid >> 6] = m;
  __syncthreads();
  m = fmaxf(fmaxf(redm[0], redm[1]), fmaxf(redm[2], redm[3]));

  float e[8];
  e[0] = __expf(a.x - m); e[1] = __expf(a.y - m);
  e[2] = __expf(a.z - m); e[3] = __expf(a.w - m);
  e[4] = __expf(b.x - m); e[5] = __expf(b.y - m);
  e[6] = __expf(b.z - m); e[7] = __expf(b.w - m);
  float s = ((e[0] + e[1]) + (e[2] + e[3])) + ((e[4] + e[5]) + (e[6] + e[7]));
#pragma unroll
  for (int o = 32; o; o >>= 1) s += __shfl_xor(s, o);
  __shared__ float reds[4];
  if ((tid & 63) == 0) reds[tid >> 6] = s;
  __syncthreads();
  s = (reds[0] + reds[1]) + (reds[2] + reds[3]);
  const float inv = 1.0f / s;

  u16* dst = (u16*)scores + row * 4096;
  uint2 w0, w1;
  w0.x = (uint32_t)f2h(e[0] * inv) | ((uint32_t)f2h(e[1] * inv) << 16);
  w0.y = (uint32_t)f2h(e[2] * inv) | ((uint32_t)f2h(e[3] * inv) << 16);
  w1.x = (uint32_t)f2h(e[4] * inv) | ((uint32_t)f2h(e[5] * inv) << 16);
  w1.y = (uint32_t)f2h(e[6] * inv) | ((uint32_t)f2h(e[7] * inv) << 16);
  ((uint2*)dst)[tid] = w0;
  ((uint2*)dst)[tid + 256] = w1;
}

// ------------------------------------------------------- layernorm (rows of 1024)
__global__ __launch_bounds__(256) void layernorm_rows(
    const float* __restrict__ y, const float* __restrict__ gamma,
    const float* __restrict__ beta, float* __restrict__ out)
{
  const long row = blockIdx.x;
  const int tid = threadIdx.x;
  float4 v = ((const float4*)(y + row * 1024))[tid];
  float s = (v.x + v.y) + (v.z + v.w);
  float q = (v.x * v.x + v.y * v.y) + (v.z * v.z + v.w * v.w);
#pragma unroll
  for (int o = 32; o; o >>= 1) { s += __shfl_xor(s, o); q += __shfl_xor(q, o); }
  __shared__ float rs[4], rq[4];
  if ((tid & 63) == 0) { rs[tid >> 6] = s; rq[tid >> 6] = q; }
  __syncthreads();
  s = (rs[0] + rs[1]) + (rs[2] + rs[3]);
  q = (rq[0] + rq[1]) + (rq[2] + rq[3]);
  const float mu = s * (1.0f / 1024.0f);
  const float var = q * (1.0f / 1024.0f) - mu * mu;
  const float rstd = rsqrtf(var + 1e-5f);
  float4 g = ((const float4*)gamma)[tid];
  float4 be = ((const float4*)beta)[tid];
  float4 o;
  o.x = (v.x - mu) * rstd * g.x + be.x;
  o.y = (v.y - mu) * rstd * g.y + be.y;
  o.z = (v.z - mu) * rstd * g.z + be.z;
  o.w = (v.w - mu) * rstd * g.w + be.w;
  __syncthreads();
  ((float4*)(out + row * 1024))[tid] = o;
}

// ------------------------------------------------------- fp32 -> fp16 (flat)
__global__ __launch_bounds__(256) void cvt_f32_f16(
    const float* __restrict__ in, u16* __restrict__ out, long n4)
{
  const long stride = (long)gridDim.x * 256;
  for (long i = (long)blockIdx.x * 256 + threadIdx.x; i < n4; i += stride) {
    float4 v = ((const float4*)in)[i];
    uint2 p;
    p.x = (uint32_t)f2h(v.x) | ((uint32_t)f2h(v.y) << 16);
    p.y = (uint32_t)f2h(v.z) | ((uint32_t)f2h(v.w) << 16);
    ((uint2*)out)[i] = p;
  }
}

// ------------------------------------------------------- transpose fp32->fp16
__global__ __launch_bounds__(256) void tw_f32(
    const float* __restrict__ in, u16* __restrict__ out, int R, int C)
{
  __shared__ float T[32][33];
  const int c0 = blockIdx.x * 32, r0 = blockIdx.y * 32;
  const int tx = threadIdx.x & 31, ty = threadIdx.x >> 5;
#pragma unroll
  for (int i = 0; i < 4; ++i)
    T[ty + i * 8][tx] = in[(long)(r0 + ty + i * 8) * C + c0 + tx];
  __syncthreads();
#pragma unroll
  for (int i = 0; i < 4; ++i)
    out[(long)(c0 + ty + i * 8) * R + r0 + tx] = f2h(T[tx][ty + i * 8]);
}

// ------------------------------------------------------- transpose u16 (per z)
__global__ __launch_bounds__(256) void transpose_u16(
    const u16* __restrict__ in, u16* __restrict__ out, int R, int C)
{
  __shared__ u16 T[32][33];
  const long zo = (long)blockIdx.z * R * C;
  const int c0 = blockIdx.x * 32, r0 = blockIdx.y * 32;
  const int tx = threadIdx.x & 31, ty = threadIdx.x >> 5;
#pragma unroll
  for (int i = 0; i < 4; ++i)
    T[ty + i * 8][tx] = in[zo + (long)(r0 + ty + i * 8) * C + c0 + tx];
  __syncthreads();
#pragma unroll
  for (int i = 0; i < 4; ++i)
    out[zo + (long)(c0 + ty + i * 8) * R + r0 + tx] = T[tx][ty + i * 8];
}

// ---------------------------------------------------------------- launch
extern "C" void kernel_launch(void* const* d_in, const int* in_sizes, int n_in,
                              void* d_out, int out_size, void* d_ws, size_t ws_size,
                              hipStream_t stream)
{
  const float* x     = (const float*)d_in[0];   // [16384,1024]
  const float* Wq    = (const float*)d_in[1];   // [1024,2048]
  const float* Wk    = (const float*)d_in[2];
  const float* Wv    = (const float*)d_in[3];
  const float* Wfc   = (const float*)d_in[4];   // [2048,1024]
  const float* bfc   = (const float*)d_in[5];   // [1024]
  const float* gamma = (const float*)d_in[6];
  const float* beta  = (const float*)d_in[7];
  float* out = (float*)d_out;

  char* ws = (char*)d_ws;

  u16* wqkvT = (u16*)(ws + 0);            // 3 x [2048][1024]
  u16* wfcT  = (u16*)(ws + 12582912);     //     [1024][2048]
  tw_f32<<<dim3(64, 32), 256, 0, stream>>>(Wq, wqkvT, 1024, 2048);
  tw_f32<<<dim3(64, 32), 256, 0, stream>>>(Wk, wqkvT + (long)2048 * 1024, 1024, 2048);
  tw_f32<<<dim3(64, 32), 256, 0, stream>>>(Wv, wqkvT + (long)2 * 2048 * 1024, 1024, 2048);
  tw_f32<<<dim3(32, 64), 256, 0, stream>>>(Wfc, wfcT, 2048, 1024);

  if (ws_size >= 251658240ULL) {
    // ---------------- Plan A: full batch, chunked attention, gemm256 ----------------
    u16*  q_  = (u16*)(ws + 16777216);      // [16384][2048] fp16 (later attx)
    u16*  k_  = (u16*)(ws + 83886080);      // [16384][2048] fp16
    u16*  vT  = (u16*)(ws + 150994944);     // [8][2048(dk)][2048(m)] fp16
    float* sc = (float*)(ws + 218103808);   // 32 MiB scores chunks
    u16*  xb  = (u16*)sc;                   // ALIAS: xb dies before sc born

    cvt_f32_f16<<<2048, 256, 0, stream>>>(x, xb, (long)16384 * 1024 / 4);

    // QKV: q,k (z = weight 0,1)
    gemm256<0><<<dim3(16, 64, 2), 512, 0, stream>>>(
        xb, wqkvT, (void*)q_, 1024, 1024, 1024, 2048,
        0L, (long)2048 * 1024, (long)16384 * 2048, nullptr, nullptr);
    // V pre-transposed per batch
    gemm256<3><<<dim3(16, 64, 1), 512, 0, stream>>>(
        xb, wqkvT + (long)2 * 2048 * 1024, (void*)vT, 1024, 1024, 1024, 2048,
        0L, 0L, 0L, nullptr, nullptr);

    // attention: 4 chunks of 512 Q-rows x 8 batches
    for (int c = 0; c < 4; ++c) {
      const u16* qc = q_ + (long)c * 512 * 2048;
      gemm256<1><<<dim3(16, 2, 8), 512, 0, stream>>>(
          qc, k_, (void*)sc, 2048, 2048, 2048, 2048,
          (long)2048 * 2048, (long)2048 * 2048, (long)512 * 2048, nullptr, nullptr);
      softmax_rows<<<4096, 256, 0, stream>>>(sc);
      gemm256<0><<<dim3(16, 2, 8), 512, 0, stream>>>(
          (const u16*)sc, vT, (void*)(q_ + (long)c * 512 * 2048), 2048, 4096, 2048, 2048,
          (long)512 * 4096, (long)2048 * 2048, (long)2048 * 2048, nullptr, nullptr);
    }

    // d_out = x + relu(attx @ Wfc + bfc)
    gemm256<2><<<dim3(8, 64, 1), 512, 0, stream>>>(
        q_, wfcT, (void*)out, 2048, 2048, 2048, 1024,
        0L, 0L, 0L, bfc, x);
  } else if (ws_size >= 109051904ULL) {
    // ---------------- Plan B: 2 batches per iteration ----------------
    u16*  xb2 = (u16*)(ws + 16777216);
    u16*  q2  = (u16*)(ws + 25165824);
    u16*  k2  = q2 + (long)2 * 2048 * 2048;
    u16*  v2  = q2 + (long)4 * 2048 * 2048;
    float* sc2 = (float*)(ws + 75497472);
    u16*  vT2   = k2;
    u16*  attx2 = q2;

    for (int p = 0; p < 4; ++p) {
      const float* xp = x + (long)p * 4096 * 1024;
      cvt_f32_f16<<<1024, 256, 0, stream>>>(xp, xb2, (long)4096 * 1024 / 4);
      for (int b = 0; b < 2; ++b)
        gemm_bt<0><<<dim3(16, 16, 3), 256, 0, stream>>>(
            xb2 + (long)b * 2048 * 1024, wqkvT, (void*)(q2 + (long)b * 2048 * 2048),
            1024, 1024, 1024, 2048,
            0L, (long)2048 * 1024, (long)2 * 2048 * 2048, nullptr, nullptr);
      gemm_bt<1><<<dim3(16, 16, 2), 256, 0, stream>>>(
          q2, k2, (void*)sc2, 2048, 2048, 2048, 2048,
          (long)2048 * 2048, (long)2048 * 2048, (long)2048 * 2048, nullptr, nullptr);
      softmax_rows<<<4096, 256, 0, stream>>>(sc2);
      transpose_u16<<<dim3(64, 64, 2), 256, 0, stream>>>(v2, vT2, 2048, 2048);
      gemm_bt<0><<<dim3(16, 16, 2), 256, 0, stream>>>(
          (const u16*)sc2, vT2, (void*)attx2, 2048, 4096, 2048, 2048,
          (long)2048 * 4096, (long)2048 * 2048, (long)2048 * 2048, nullptr, nullptr);
      gemm_bt<2><<<dim3(8, 32, 1), 256, 0, stream>>>(
          attx2, wfcT, (void*)(out + (long)p * 4096 * 1024), 2048, 2048, 2048, 1024,
          0L, 0L, 0L, bfc, xp);
    }
  } else {
    // ---------------- Plan C: per-batch fallback ----------------
    u16*  xb_b   = (u16*)(ws + 16777216);
    u16*  qkv_b  = (u16*)(ws + 20971520);
    u16*  q_b    = qkv_b;
    u16*  k_b    = qkv_b + (long)2048 * 2048;
    u16*  v_b    = qkv_b + (long)2 * 2048 * 2048;
    float* sc_b  = (float*)(ws + 46137344);
    u16*  vT_b   = k_b;
    u16*  attx_b = q_b;

    for (int b = 0; b < 8; ++b) {
      const float* x_b = x + (long)b * 2048 * 1024;
      cvt_f32_f16<<<512, 256, 0, stream>>>(x_b, xb_b, (long)2048 * 1024 / 4);
      gemm_bt<0><<<dim3(16, 16, 3), 256, 0, stream>>>(
          xb_b, wqkvT, (void*)qkv_b, 1024, 1024, 1024, 2048,
          0L, (long)2048 * 1024, (long)2048 * 2048, nullptr, nullptr);
      gemm_bt<1><<<dim3(16, 16, 1), 256, 0, stream>>>(
          q_b, k_b, (void*)sc_b, 2048, 2048, 2048, 2048,
          0L, 0L, 0L, nullptr, nullptr);
      softmax_rows<<<2048, 256, 0, stream>>>(sc_b);
      transpose_u16<<<dim3(64, 64, 1), 256, 0, stream>>>(v_b, vT_b, 2048, 2048);
      gemm_bt<0><<<dim3(16, 16, 1), 256, 0, stream>>>(
          (const u16*)sc_b, vT_b, (void*)attx_b, 2048, 4096, 2048, 2048,
          0L, 0L, 0L, nullptr, nullptr);
      gemm_bt<2><<<dim3(8, 16, 1), 256, 0, stream>>>(
          attx_b, wfcT, (void*)(out + (long)b * 2048 * 1024), 2048, 2048, 2048, 1024,
          0L, 0L, 0L, bfc, x_b);
    }
  }

  layernorm_rows<<<16384, 256, 0, stream>>>(out, gamma, beta, out);
}